// Round 1
// baseline (746.779 us; speedup 1.0000x reference)
//
#include <hip/hip_runtime.h>

// Problem constants: B=4, L=S=2048, H=8, E=D=64
#define LDIM 2048
#define HDIM 8
#define EDIM 64
#define STRIDE 512  // H*E contiguous stride for [B,L,H,E] tensors

// ---------------------------------------------------------------------------
// Kernel 1: KM[bh][e][t] = sum_s K[b,s,h,e] * M[s,t]
// One block computes a 64(e) x 64(t) tile; grid = (t_tiles=32, bh=32).
// Treated as a 2048x2048x2048 fp32 GEMM (A[r=(b,h,e),s] = K[b,s,h,e]).
// ---------------------------------------------------------------------------
__global__ __launch_bounds__(256) void km_kernel(
    const float* __restrict__ K, const float* __restrict__ M,
    float* __restrict__ KM) {
  const int t0 = blockIdx.x * 64;
  const int bh = blockIdx.y;
  const int b = bh >> 3, h = bh & 7;
  __shared__ float Ks[64][68];  // [s][e], pad 68 keeps float4 rows 16B-aligned
  __shared__ float Ms[64][68];  // [s][t]
  const int tid = threadIdx.x;
  const int tx = tid & 15, ty = tid >> 4;

  float acc[4][4] = {};
  const float* Kb = K + ((size_t)b * LDIM * HDIM + h) * EDIM;
  const float* Mb = M + t0;

  for (int s0 = 0; s0 < 2048; s0 += 64) {
    __syncthreads();
#pragma unroll
    for (int k = 0; k < 4; ++k) {
      const int vi = k * 256 + tid;   // 1024 float4s per array
      const int r = vi >> 4;          // s row 0..63
      const int c = (vi & 15) << 2;   // col 0..60
      *(float4*)&Ks[r][c] = *(const float4*)(Kb + (size_t)(s0 + r) * STRIDE + c);
      *(float4*)&Ms[r][c] = *(const float4*)(Mb + (size_t)(s0 + r) * 2048 + c);
    }
    __syncthreads();
#pragma unroll 8
    for (int s = 0; s < 64; ++s) {
      const float4 a = *(const float4*)&Ks[s][ty << 2];
      const float4 bb = *(const float4*)&Ms[s][tx << 2];
      const float av[4] = {a.x, a.y, a.z, a.w};
      const float bv[4] = {bb.x, bb.y, bb.z, bb.w};
#pragma unroll
      for (int i = 0; i < 4; ++i)
#pragma unroll
        for (int j = 0; j < 4; ++j)
          acc[i][j] = fmaf(av[i], bv[j], acc[i][j]);
    }
  }

  float* out = KM + ((size_t)bh * 64 + (ty << 2)) * 2048 + t0 + (tx << 2);
#pragma unroll
  for (int i = 0; i < 4; ++i) {
    const float4 r = make_float4(acc[i][0], acc[i][1], acc[i][2], acc[i][3]);
    *(float4*)(out + (size_t)i * 2048) = r;
  }
}

// ---------------------------------------------------------------------------
// Kernel 2: flash-style attention using KM as the [E x S] "key" matrix.
//   z = (Q_tile @ KM_tile) / 8 ; causal mask t>l ; online softmax ; O += P @ V
// One block = 64 query rows for one (b,h); grid = (l_tiles=32, bh=32).
// ---------------------------------------------------------------------------
__global__ __launch_bounds__(256) void attn_kernel(
    const float* __restrict__ Q, const float* __restrict__ KM,
    const float* __restrict__ V, float* __restrict__ O) {
  const int lt = blockIdx.x;
  const int l0 = lt * 64;
  const int bh = blockIdx.y;
  const int b = bh >> 3, h = bh & 7;

  __shared__ float Qs[64][68];   // [e][l] (transposed for b128 reads along l)
  __shared__ float KMs[64][68];  // [e][t]
  __shared__ float Ps[64][68];   // [t][l] (transposed for b128 reads along l)
  __shared__ float Vs[64][68];   // [t][d]

  const int tid = threadIdx.x;
  const int tx = tid & 15, ty = tid >> 4;

  // Stage Q tile transposed: Qs[e][l] = Q[b, l0+l, h, e]
  const float* Qb = Q + ((size_t)b * LDIM * HDIM + h) * EDIM;
#pragma unroll
  for (int k = 0; k < 4; ++k) {
    const int vi = k * 256 + tid;
    const int l = vi >> 4;
    const int e = (vi & 15) << 2;
    const float4 q = *(const float4*)(Qb + (size_t)(l0 + l) * STRIDE + e);
    Qs[e + 0][l] = q.x;
    Qs[e + 1][l] = q.y;
    Qs[e + 2][l] = q.z;
    Qs[e + 3][l] = q.w;
  }

  float o[4][4] = {};
  float mrow[4] = {-1e30f, -1e30f, -1e30f, -1e30f};
  float lrow[4] = {};

  const float* KMb = KM + (size_t)bh * 64 * 2048;
  const float* Vb = V + ((size_t)b * LDIM * HDIM + h) * EDIM;

  for (int jt = 0; jt <= lt; ++jt) {
    const int t0 = jt * 64;
    __syncthreads();  // previous PV reads of Ps/Vs + first-iter Qs writes done
#pragma unroll
    for (int k = 0; k < 4; ++k) {
      const int vi = k * 256 + tid;
      const int r = vi >> 4;
      const int c = (vi & 15) << 2;
      *(float4*)&KMs[r][c] = *(const float4*)(KMb + (size_t)r * 2048 + t0 + c);
      *(float4*)&Vs[r][c] = *(const float4*)(Vb + (size_t)(t0 + r) * STRIDE + c);
    }
    __syncthreads();

    // S = Q @ KM  (each thread: 4 l-rows x 4 t-cols)
    float s[4][4] = {};
#pragma unroll 8
    for (int e = 0; e < 64; ++e) {
      const float4 a = *(const float4*)&Qs[e][ty << 2];
      const float4 bb = *(const float4*)&KMs[e][tx << 2];
      const float av[4] = {a.x, a.y, a.z, a.w};
      const float bv[4] = {bb.x, bb.y, bb.z, bb.w};
#pragma unroll
      for (int i = 0; i < 4; ++i)
#pragma unroll
        for (int j = 0; j < 4; ++j)
          s[i][j] = fmaf(av[i], bv[j], s[i][j]);
    }

    // scale + causal mask + online softmax
    const bool diag = (jt == lt);
    float p[4][4];
#pragma unroll
    for (int i = 0; i < 4; ++i) {
      const int lg = l0 + (ty << 2) + i;
      float z[4];
#pragma unroll
      for (int j = 0; j < 4; ++j) {
        z[j] = s[i][j] * 0.125f;
        if (diag && (t0 + (tx << 2) + j > lg)) z[j] = -1e30f;
      }
      float mx = fmaxf(fmaxf(z[0], z[1]), fmaxf(z[2], z[3]));
#pragma unroll
      for (int off = 1; off < 16; off <<= 1) mx = fmaxf(mx, __shfl_xor(mx, off));
      const float mnew = fmaxf(mrow[i], mx);
      const float f = __expf(mrow[i] - mnew);
      mrow[i] = mnew;
      float rs = 0.f;
#pragma unroll
      for (int j = 0; j < 4; ++j) {
        p[i][j] = __expf(z[j] - mnew);
        rs += p[i][j];
      }
#pragma unroll
      for (int off = 1; off < 16; off <<= 1) rs += __shfl_xor(rs, off);
      lrow[i] = lrow[i] * f + rs;
#pragma unroll
      for (int j = 0; j < 4; ++j) o[i][j] *= f;
    }

    // Write P transposed: Ps[t][l]; thread owns 4 consecutive l per t -> float4
#pragma unroll
    for (int j = 0; j < 4; ++j) {
      const float4 pv = make_float4(p[0][j], p[1][j], p[2][j], p[3][j]);
      *(float4*)&Ps[(tx << 2) + j][ty << 2] = pv;
    }
    __syncthreads();

    // O += P @ V
#pragma unroll 8
    for (int t = 0; t < 64; ++t) {
      const float4 a = *(const float4*)&Ps[t][ty << 2];
      const float4 bb = *(const float4*)&Vs[t][tx << 2];
      const float av[4] = {a.x, a.y, a.z, a.w};
      const float bv[4] = {bb.x, bb.y, bb.z, bb.w};
#pragma unroll
      for (int i = 0; i < 4; ++i)
#pragma unroll
        for (int j = 0; j < 4; ++j)
          o[i][j] = fmaf(av[i], bv[j], o[i][j]);
    }
  }

  // Epilogue: normalize and store. O[b, l, h, d]
  float* Ob = O + ((size_t)b * LDIM * HDIM + h) * EDIM;
#pragma unroll
  for (int i = 0; i < 4; ++i) {
    const float inv = 1.0f / lrow[i];
    const float4 r =
        make_float4(o[i][0] * inv, o[i][1] * inv, o[i][2] * inv, o[i][3] * inv);
    *(float4*)(Ob + (size_t)(l0 + (ty << 2) + i) * STRIDE + (tx << 2)) = r;
  }
}

extern "C" void kernel_launch(void* const* d_in, const int* in_sizes, int n_in,
                              void* d_out, int out_size, void* d_ws, size_t ws_size,
                              hipStream_t stream) {
  const float* Q = (const float*)d_in[0];  // [B,L,H,E]
  const float* K = (const float*)d_in[1];  // [B,S,H,E]
  const float* V = (const float*)d_in[2];  // [B,S,H,D]
  const float* M = (const float*)d_in[3];  // [S,S]
  float* Out = (float*)d_out;              // [B,L,H,D]
  float* KM = (float*)d_ws;                // [BH=32][E=64][S=2048] fp32 = 16 MB

  km_kernel<<<dim3(32, 32), 256, 0, stream>>>(K, M, KM);
  attn_kernel<<<dim3(32, 32), 256, 0, stream>>>(Q, KM, V, Out);
}

// Round 2
// 222.829 us; speedup vs baseline: 3.3514x; 3.3514x over previous
//
#include <hip/hip_runtime.h>

// B=4, L=S=2048, H=8, E=D=64.  Algorithm: KM[bh][t][e] = sum_s K[b,s,h,e]*M[s,t]
// (16 MB, hi/lo bf16), then flash attention z = Q*KM/8, causal, online softmax.
// Split-bf16 (hi+lo) MFMA for both GEMMs: acc += Ah*Bh + Ah*Bl + Al*Bh.

typedef short bf16x8 __attribute__((ext_vector_type(8)));
typedef float f32x4 __attribute__((ext_vector_type(4)));
typedef unsigned short u16x8 __attribute__((ext_vector_type(8)));

typedef __attribute__((address_space(1))) const void gvoid;
typedef __attribute__((address_space(3))) void lvoid;

__device__ __forceinline__ unsigned short f2bf(float x) {
  unsigned int u = __float_as_uint(x);
  u += 0x7FFFu + ((u >> 16) & 1u);
  return (unsigned short)(u >> 16);
}
__device__ __forceinline__ float bf2f(unsigned short h) {
  return __uint_as_float(((unsigned int)h) << 16);
}

__device__ __forceinline__ void gload16(const unsigned short* g, unsigned short* l) {
  __builtin_amdgcn_global_load_lds((gvoid*)g, (lvoid*)l, 16, 0, 0);
}

// Stage a [rows][64 bf16] tile (row stride 128B in LDS) from global rows of
// stride gstride (elements). LDS dest is LINEAR (global_load_lds requirement);
// the XOR swizzle byte^=( (row&7)<<4 ) is applied by pre-swizzling the global
// SOURCE address; readers apply the same XOR. rows must be a multiple of 8.
__device__ __forceinline__ void stage_tile(const unsigned short* __restrict__ g,
                                           int gstride, unsigned short* l,
                                           int rows, int tid) {
  const int lane = tid & 63, w = tid >> 6;
  const int nch = rows << 3;  // 16B chunks
  for (int c0 = (w << 6); c0 < nch; c0 += 256) {
    const int c = c0 + lane;
    const int row = c >> 3;
    const int bir = (c & 7) << 4;                 // byte-in-row of LDS chunk
    const int sb = bir ^ ((row & 7) << 4);        // inverse-swizzled source byte
    gload16(g + (size_t)row * gstride + (sb >> 1), l + (size_t)c0 * 8);
  }
}

// swizzled byte offset inside a [*][64 bf16] tile
__device__ __forceinline__ int swz(int row, int byteInRow) {
  return row * 128 + (byteInRow ^ ((row & 7) << 4));
}

// ---------------------------------------------------------------------------
// prep_m: Mt_hi/lo[t][s] = split(M[s][t])   (transpose 2048x2048)
// ---------------------------------------------------------------------------
__global__ __launch_bounds__(256) void prep_m(const float* __restrict__ M,
                                              unsigned short* __restrict__ Mh,
                                              unsigned short* __restrict__ Ml) {
  __shared__ float Ts[64][68];
  const int s0 = blockIdx.x << 6, t0 = blockIdx.y << 6;
  const int tid = threadIdx.x, r = tid >> 2, c0 = (tid & 3) << 4;
  const float* src = M + (size_t)(s0 + r) * 2048 + t0 + c0;
#pragma unroll
  for (int j = 0; j < 4; ++j)
    *(float4*)&Ts[r][c0 + 4 * j] = *(const float4*)(src + 4 * j);
  __syncthreads();
  u16x8 h0, h1, l0v, l1v;
#pragma unroll
  for (int j = 0; j < 8; ++j) {
    float x = Ts[c0 + j][r];
    unsigned short hh = f2bf(x);
    h0[j] = hh; l0v[j] = f2bf(x - bf2f(hh));
  }
#pragma unroll
  for (int j = 8; j < 16; ++j) {
    float x = Ts[c0 + j][r];
    unsigned short hh = f2bf(x);
    h1[j - 8] = hh; l1v[j - 8] = f2bf(x - bf2f(hh));
  }
  const size_t o = (size_t)(t0 + r) * 2048 + s0 + c0;
  *(u16x8*)(Mh + o) = h0; *(u16x8*)(Mh + o + 8) = h1;
  *(u16x8*)(Ml + o) = l0v; *(u16x8*)(Ml + o + 8) = l1v;
}

// ---------------------------------------------------------------------------
// prep_kv: Dst[bh][e][s] = split(src[b,s,h,e])  (per-bh transpose, 64 x 2048)
// has_lo=0 -> single bf16 plane (V)
// ---------------------------------------------------------------------------
__global__ __launch_bounds__(256) void prep_kv(const float* __restrict__ src4d,
                                               unsigned short* __restrict__ Dh,
                                               unsigned short* __restrict__ Dl,
                                               int has_lo) {
  __shared__ float Ts[64][68];
  const int s0 = blockIdx.x << 6, bh = blockIdx.y;
  const int b = bh >> 3, h = bh & 7;
  const int tid = threadIdx.x, r = tid >> 2, c0 = (tid & 3) << 4;
  const float* src = src4d + ((size_t)(b * 2048 + s0 + r) * 8 + h) * 64 + c0;
#pragma unroll
  for (int j = 0; j < 4; ++j)
    *(float4*)&Ts[r][c0 + 4 * j] = *(const float4*)(src + 4 * j);
  __syncthreads();
  u16x8 h0, h1, l0v, l1v;
#pragma unroll
  for (int j = 0; j < 8; ++j) {
    float x = Ts[c0 + j][r];
    unsigned short hh = f2bf(x);
    h0[j] = hh; l0v[j] = f2bf(x - bf2f(hh));
  }
#pragma unroll
  for (int j = 8; j < 16; ++j) {
    float x = Ts[c0 + j][r];
    unsigned short hh = f2bf(x);
    h1[j - 8] = hh; l1v[j - 8] = f2bf(x - bf2f(hh));
  }
  const size_t o = ((size_t)bh * 64 + r) * 2048 + s0 + c0;
  *(u16x8*)(Dh + o) = h0; *(u16x8*)(Dh + o + 8) = h1;
  if (has_lo) { *(u16x8*)(Dl + o) = l0v; *(u16x8*)(Dl + o + 8) = l1v; }
}

// ---------------------------------------------------------------------------
// km_mfma: KM[bh][t][e] (hi/lo bf16) = sum_s M[s][t]*K[s][e]
// block = 128t x 64e, 4 waves of 32t x 64e. A=Mt[t][s], B=Kt[e][s].
// ---------------------------------------------------------------------------
__global__ __launch_bounds__(256) void km_mfma(
    const unsigned short* __restrict__ Mth, const unsigned short* __restrict__ Mtl,
    const unsigned short* __restrict__ Kth, const unsigned short* __restrict__ Ktl,
    unsigned short* __restrict__ KMh, unsigned short* __restrict__ KMl) {
  __shared__ __attribute__((aligned(16))) unsigned short sm[24576];  // 48 KB
  unsigned short* MtH = sm;            // [128][64]
  unsigned short* MtL = sm + 8192;
  unsigned short* KtH = sm + 16384;    // [64][64]
  unsigned short* KtL = sm + 20480;
  const int tid = threadIdx.x, lane = tid & 63, w = tid >> 6;
  const int g = lane >> 4, li = lane & 15;
  const int t0 = blockIdx.x << 7;
  const int bh = blockIdx.y;
  const unsigned short* KtHb = Kth + (size_t)bh * 64 * 2048;
  const unsigned short* KtLb = Ktl + (size_t)bh * 64 * 2048;

  f32x4 acc[2][4];
#pragma unroll
  for (int mi = 0; mi < 2; ++mi)
#pragma unroll
    for (int ni = 0; ni < 4; ++ni) acc[mi][ni] = (f32x4){0.f, 0.f, 0.f, 0.f};

  for (int s0 = 0; s0 < 2048; s0 += 64) {
    __syncthreads();
    stage_tile(Mth + (size_t)t0 * 2048 + s0, 2048, MtH, 128, tid);
    stage_tile(Mtl + (size_t)t0 * 2048 + s0, 2048, MtL, 128, tid);
    stage_tile(KtHb + s0, 2048, KtH, 64, tid);
    stage_tile(KtLb + s0, 2048, KtL, 64, tid);
    asm volatile("s_waitcnt vmcnt(0)" ::: "memory");
    __syncthreads();
#pragma unroll
    for (int kk = 0; kk < 2; ++kk) {
      const int kb = (kk * 32 + 8 * g) * 2;
      bf16x8 aH[2], aL[2];
#pragma unroll
      for (int mi = 0; mi < 2; ++mi) {
        const int row = (w << 5) + (mi << 4) + li;
        aH[mi] = *(const bf16x8*)((const char*)MtH + swz(row, kb));
        aL[mi] = *(const bf16x8*)((const char*)MtL + swz(row, kb));
      }
#pragma unroll
      for (int ni = 0; ni < 4; ++ni) {
        const int row = (ni << 4) + li;
        const int off = swz(row, kb);
        const bf16x8 bH = *(const bf16x8*)((const char*)KtH + off);
        const bf16x8 bL = *(const bf16x8*)((const char*)KtL + off);
#pragma unroll
        for (int mi = 0; mi < 2; ++mi) {
          acc[mi][ni] = __builtin_amdgcn_mfma_f32_16x16x32_bf16(aH[mi], bH, acc[mi][ni], 0, 0, 0);
          acc[mi][ni] = __builtin_amdgcn_mfma_f32_16x16x32_bf16(aH[mi], bL, acc[mi][ni], 0, 0, 0);
          acc[mi][ni] = __builtin_amdgcn_mfma_f32_16x16x32_bf16(aL[mi], bH, acc[mi][ni], 0, 0, 0);
        }
      }
    }
  }
  // store split KM: D rows t = t0 + w*32 + mi*16 + 4g + r, cols e = ni*16 + li
  const size_t base = (size_t)bh * 2048 * 64;
#pragma unroll
  for (int mi = 0; mi < 2; ++mi)
#pragma unroll
    for (int r = 0; r < 4; ++r) {
      const int trow = t0 + (w << 5) + (mi << 4) + (g << 2) + r;
#pragma unroll
      for (int ni = 0; ni < 4; ++ni) {
        const float x = acc[mi][ni][r];
        const unsigned short hh = f2bf(x);
        const size_t idx = base + (size_t)trow * 64 + (ni << 4) + li;
        KMh[idx] = hh;
        KMl[idx] = f2bf(x - bf2f(hh));
      }
    }
}

// ---------------------------------------------------------------------------
// attn_mfma: per (lt,bh): 64 q-rows, loop kv tiles of 64.
// wave = 16l x 64t. z=Q*KM (split, 3 mfma), online softmax (lane-local rows),
// P -> per-wave LDS -> PV mfma (single bf16).
// ---------------------------------------------------------------------------
__global__ __launch_bounds__(256) void attn_mfma(
    const float* __restrict__ Q, const unsigned short* __restrict__ KMh,
    const unsigned short* __restrict__ KMl, const unsigned short* __restrict__ Vt,
    float* __restrict__ Out) {
  __shared__ __attribute__((aligned(16))) unsigned short sm[24576];  // 48 KB
  unsigned short* QH = sm;          // [64 l][64 e]
  unsigned short* QL = sm + 4096;
  unsigned short* KH = sm + 8192;   // [64 t][64 e]
  unsigned short* KL = sm + 12288;
  unsigned short* VT = sm + 16384;  // [64 d][64 t]
  const int tid = threadIdx.x, lane = tid & 63, w = tid >> 6;
  const int g = lane >> 4, li = lane & 15;
  unsigned short* PS = sm + 20480 + (w << 10);  // per-wave [16 l][64 t]

  const int lt = 31 - (int)blockIdx.x;  // big blocks dispatch first
  const int bh = blockIdx.y, b = bh >> 3, h = bh & 7;
  const int l0 = lt << 6;

  {  // stage Q: convert fp32 -> hi/lo bf16, swizzled LDS writes
    const int row = tid >> 2, e0 = (tid & 3) << 4;
    const float* src = Q + ((size_t)(b * 2048 + l0 + row) * 8 + h) * 64 + e0;
#pragma unroll
    for (int half = 0; half < 2; ++half) {
      const float4 v0 = *(const float4*)(src + half * 8);
      const float4 v1 = *(const float4*)(src + half * 8 + 4);
      const float xs[8] = {v0.x, v0.y, v0.z, v0.w, v1.x, v1.y, v1.z, v1.w};
      u16x8 hv, lv;
#pragma unroll
      for (int j = 0; j < 8; ++j) {
        const unsigned short hh = f2bf(xs[j]);
        hv[j] = hh; lv[j] = f2bf(xs[j] - bf2f(hh));
      }
      const int off = swz(row, (e0 + half * 8) * 2);
      *(u16x8*)((char*)QH + off) = hv;
      *(u16x8*)((char*)QL + off) = lv;
    }
  }

  f32x4 o[4];
#pragma unroll
  for (int dn = 0; dn < 4; ++dn) o[dn] = (f32x4){0.f, 0.f, 0.f, 0.f};
  float mrow[4] = {-1e30f, -1e30f, -1e30f, -1e30f};
  float lrow[4] = {0.f, 0.f, 0.f, 0.f};

  const unsigned short* KHb = KMh + (size_t)bh * 2048 * 64;
  const unsigned short* KLb = KMl + (size_t)bh * 2048 * 64;
  const unsigned short* VTb = Vt + (size_t)bh * 64 * 2048;

  for (int jt = 0; jt <= lt; ++jt) {
    __syncthreads();
    stage_tile(KHb + (size_t)jt * 64 * 64, 64, KH, 64, tid);
    stage_tile(KLb + (size_t)jt * 64 * 64, 64, KL, 64, tid);
    stage_tile(VTb + jt * 64, 2048, VT, 64, tid);
    asm volatile("s_waitcnt vmcnt(0)" ::: "memory");
    __syncthreads();

    // z = Q*KM (rows w*16+li, cols nt*16+li over this 64-t tile)
    f32x4 z[4];
#pragma unroll
    for (int nt = 0; nt < 4; ++nt) z[nt] = (f32x4){0.f, 0.f, 0.f, 0.f};
#pragma unroll
    for (int kk = 0; kk < 2; ++kk) {
      const int kb = (kk * 32 + 8 * g) * 2;
      const int qrow = (w << 4) + li;
      const int qoff = swz(qrow, kb);
      const bf16x8 aH = *(const bf16x8*)((const char*)QH + qoff);
      const bf16x8 aL = *(const bf16x8*)((const char*)QL + qoff);
#pragma unroll
      for (int nt = 0; nt < 4; ++nt) {
        const int trow = (nt << 4) + li;
        const int toff = swz(trow, kb);
        const bf16x8 bH = *(const bf16x8*)((const char*)KH + toff);
        const bf16x8 bL = *(const bf16x8*)((const char*)KL + toff);
        z[nt] = __builtin_amdgcn_mfma_f32_16x16x32_bf16(aH, bH, z[nt], 0, 0, 0);
        z[nt] = __builtin_amdgcn_mfma_f32_16x16x32_bf16(aH, bL, z[nt], 0, 0, 0);
        z[nt] = __builtin_amdgcn_mfma_f32_16x16x32_bf16(aL, bH, z[nt], 0, 0, 0);
      }
    }

    // online softmax; lane holds rows (4g+r), cols nt*16+li
    const bool diag = (jt == lt);
#pragma unroll
    for (int r = 0; r < 4; ++r) {
      const int lrow_in = (w << 4) + (g << 2) + r;  // row within 64
      float zz[4];
#pragma unroll
      for (int nt = 0; nt < 4; ++nt) {
        zz[nt] = z[nt][r] * 0.125f;
        if (diag && ((nt << 4) + li > lrow_in)) zz[nt] = -1e30f;
      }
      float mx = fmaxf(fmaxf(zz[0], zz[1]), fmaxf(zz[2], zz[3]));
#pragma unroll
      for (int off = 1; off < 16; off <<= 1) mx = fmaxf(mx, __shfl_xor(mx, off));
      const float mnew = fmaxf(mrow[r], mx);
      const float fs = __expf(mrow[r] - mnew);
      mrow[r] = mnew;
      float rs = 0.f;
      unsigned short pb[4];
#pragma unroll
      for (int nt = 0; nt < 4; ++nt) {
        const float p = __expf(zz[nt] - mnew);
        rs += p;
        pb[nt] = f2bf(p);
      }
#pragma unroll
      for (int off = 1; off < 16; off <<= 1) rs += __shfl_xor(rs, off);
      lrow[r] = lrow[r] * fs + rs;
#pragma unroll
      for (int dn = 0; dn < 4; ++dn) o[dn][r] *= fs;
      // P -> per-wave LDS (swizzled, row = 4g+r)
      const int prow = (g << 2) + r;
#pragma unroll
      for (int nt = 0; nt < 4; ++nt) {
        const int byte = ((((nt << 4) + li) * 2) ^ ((prow & 7) << 4));
        *(unsigned short*)((char*)PS + prow * 128 + byte) = pb[nt];
      }
    }

    // O += P*V  (A=P rows li, B=Vt rows d; DS ops in-order within wave)
#pragma unroll
    for (int kk = 0; kk < 2; ++kk) {
      const int kb = (kk * 32 + 8 * g) * 2;
      const bf16x8 pa = *(const bf16x8*)((const char*)PS + swz(li, kb));
#pragma unroll
      for (int dn = 0; dn < 4; ++dn) {
        const int drow = (dn << 4) + li;
        const bf16x8 vb = *(const bf16x8*)((const char*)VT + swz(drow, kb));
        o[dn] = __builtin_amdgcn_mfma_f32_16x16x32_bf16(pa, vb, o[dn], 0, 0, 0);
      }
    }
  }

  // epilogue: normalize + store fp32
  const size_t ob = ((size_t)(b * 2048 + l0 + (w << 4)) * 8 + h) * 64;
#pragma unroll
  for (int r = 0; r < 4; ++r) {
    const float inv = 1.f / lrow[r];
    const int lr = (g << 2) + r;
#pragma unroll
    for (int dn = 0; dn < 4; ++dn)
      Out[ob + (size_t)lr * 512 + (dn << 4) + li] = o[dn][r] * inv;
  }
}

extern "C" void kernel_launch(void* const* d_in, const int* in_sizes, int n_in,
                              void* d_out, int out_size, void* d_ws, size_t ws_size,
                              hipStream_t stream) {
  const float* Q = (const float*)d_in[0];
  const float* K = (const float*)d_in[1];
  const float* V = (const float*)d_in[2];
  const float* M = (const float*)d_in[3];
  float* Out = (float*)d_out;
  char* ws = (char*)d_ws;
  const size_t MB = 1u << 20;
  unsigned short* Mth = (unsigned short*)(ws);            // [2048 t][2048 s]
  unsigned short* Mtl = (unsigned short*)(ws + 8 * MB);
  unsigned short* Kth = (unsigned short*)(ws + 16 * MB);  // [32 bh][64 e][2048 s]
  unsigned short* Ktl = (unsigned short*)(ws + 24 * MB);
  unsigned short* Vts = (unsigned short*)(ws + 32 * MB);  // [32 bh][64 d][2048 s]
  unsigned short* KMh = (unsigned short*)(ws + 40 * MB);  // [32 bh][2048 t][64 e]
  unsigned short* KMl = (unsigned short*)(ws + 48 * MB);

  prep_m<<<dim3(32, 32), 256, 0, stream>>>(M, Mth, Mtl);
  prep_kv<<<dim3(32, 32), 256, 0, stream>>>(K, Kth, Ktl, 1);
  prep_kv<<<dim3(32, 32), 256, 0, stream>>>(V, Vts, (unsigned short*)nullptr, 0);
  km_mfma<<<dim3(16, 32), 256, 0, stream>>>(Mth, Mtl, Kth, Ktl, KMh, KMl);
  attn_mfma<<<dim3(32, 32), 256, 0, stream>>>(Q, KMh, KMl, Vts, Out);
}

// Round 3
// 179.885 us; speedup vs baseline: 4.1514x; 1.2387x over previous
//
#include <hip/hip_runtime.h>

// B=4, L=S=2048, H=8, E=D=64.  KM[bh][t][e] = sum_s K[b,s,h,e]*M[s,t] (split
// bf16 hi/lo), then flash attention z = Q*KM/8, causal, online softmax.
// Round 3: attn rebuilt on 32x32x16 MFMA with swapped operands (lane-local
// softmax rows), Q fragments in registers, balanced big-first grid.

typedef short bf16x8 __attribute__((ext_vector_type(8)));
typedef float f32x4 __attribute__((ext_vector_type(4)));
typedef float f32x16 __attribute__((ext_vector_type(16)));
typedef unsigned short u16x8 __attribute__((ext_vector_type(8)));

typedef __attribute__((address_space(1))) const void gvoid;
typedef __attribute__((address_space(3))) void lvoid;

__device__ __forceinline__ unsigned short f2bf(float x) {
  unsigned int u = __float_as_uint(x);
  u += 0x7FFFu + ((u >> 16) & 1u);
  return (unsigned short)(u >> 16);
}
__device__ __forceinline__ float bf2f(unsigned short h) {
  return __uint_as_float(((unsigned int)h) << 16);
}

__device__ __forceinline__ void gload16(const unsigned short* g, unsigned short* l) {
  __builtin_amdgcn_global_load_lds((gvoid*)g, (lvoid*)l, 16, 0, 0);
}

// Stage a [rows][64 bf16] tile (row stride 128B in LDS) from global rows of
// stride gstride. LDS dest LINEAR (global_load_lds rule); XOR swizzle
// byte^=((row&7)<<4) realized by pre-swizzling the global SOURCE address.
__device__ __forceinline__ void stage_tile(const unsigned short* __restrict__ g,
                                           int gstride, unsigned short* l,
                                           int rows, int tid) {
  const int lane = tid & 63, w = tid >> 6;
  const int nch = rows << 3;  // 16B chunks
  for (int c0 = (w << 6); c0 < nch; c0 += 256) {
    const int c = c0 + lane;
    const int row = c >> 3;
    const int bir = (c & 7) << 4;
    const int sb = bir ^ ((row & 7) << 4);
    gload16(g + (size_t)row * gstride + (sb >> 1), l + (size_t)c0 * 8);
  }
}

// swizzled byte offset inside a [*][64 bf16] tile
__device__ __forceinline__ int swz(int row, int byteInRow) {
  return row * 128 + (byteInRow ^ ((row & 7) << 4));
}

// ---------------------------------------------------------------------------
// prep_m: Mt_hi/lo[t][s] = split(M[s][t])
// ---------------------------------------------------------------------------
__global__ __launch_bounds__(256) void prep_m(const float* __restrict__ M,
                                              unsigned short* __restrict__ Mh,
                                              unsigned short* __restrict__ Ml) {
  __shared__ float Ts[64][68];
  const int s0 = blockIdx.x << 6, t0 = blockIdx.y << 6;
  const int tid = threadIdx.x, r = tid >> 2, c0 = (tid & 3) << 4;
  const float* src = M + (size_t)(s0 + r) * 2048 + t0 + c0;
#pragma unroll
  for (int j = 0; j < 4; ++j)
    *(float4*)&Ts[r][c0 + 4 * j] = *(const float4*)(src + 4 * j);
  __syncthreads();
  u16x8 h0, h1, l0v, l1v;
#pragma unroll
  for (int j = 0; j < 8; ++j) {
    float x = Ts[c0 + j][r];
    unsigned short hh = f2bf(x);
    h0[j] = hh; l0v[j] = f2bf(x - bf2f(hh));
  }
#pragma unroll
  for (int j = 8; j < 16; ++j) {
    float x = Ts[c0 + j][r];
    unsigned short hh = f2bf(x);
    h1[j - 8] = hh; l1v[j - 8] = f2bf(x - bf2f(hh));
  }
  const size_t o = (size_t)(t0 + r) * 2048 + s0 + c0;
  *(u16x8*)(Mh + o) = h0; *(u16x8*)(Mh + o + 8) = h1;
  *(u16x8*)(Ml + o) = l0v; *(u16x8*)(Ml + o + 8) = l1v;
}

// ---------------------------------------------------------------------------
// prep_kv: Dst[bh][e][s] = split(src[b,s,h,e]); has_lo=0 -> single plane (V)
// ---------------------------------------------------------------------------
__global__ __launch_bounds__(256) void prep_kv(const float* __restrict__ src4d,
                                               unsigned short* __restrict__ Dh,
                                               unsigned short* __restrict__ Dl,
                                               int has_lo) {
  __shared__ float Ts[64][68];
  const int s0 = blockIdx.x << 6, bh = blockIdx.y;
  const int b = bh >> 3, h = bh & 7;
  const int tid = threadIdx.x, r = tid >> 2, c0 = (tid & 3) << 4;
  const float* src = src4d + ((size_t)(b * 2048 + s0 + r) * 8 + h) * 64 + c0;
#pragma unroll
  for (int j = 0; j < 4; ++j)
    *(float4*)&Ts[r][c0 + 4 * j] = *(const float4*)(src + 4 * j);
  __syncthreads();
  u16x8 h0, h1, l0v, l1v;
#pragma unroll
  for (int j = 0; j < 8; ++j) {
    float x = Ts[c0 + j][r];
    unsigned short hh = f2bf(x);
    h0[j] = hh; l0v[j] = f2bf(x - bf2f(hh));
  }
#pragma unroll
  for (int j = 8; j < 16; ++j) {
    float x = Ts[c0 + j][r];
    unsigned short hh = f2bf(x);
    h1[j - 8] = hh; l1v[j - 8] = f2bf(x - bf2f(hh));
  }
  const size_t o = ((size_t)bh * 64 + r) * 2048 + s0 + c0;
  *(u16x8*)(Dh + o) = h0; *(u16x8*)(Dh + o + 8) = h1;
  if (has_lo) { *(u16x8*)(Dl + o) = l0v; *(u16x8*)(Dl + o + 8) = l1v; }
}

// ---------------------------------------------------------------------------
// km_mfma: KM[bh][t][e] (hi/lo) = sum_s M[s][t]*K[s][e]  (unchanged, proven)
// ---------------------------------------------------------------------------
__global__ __launch_bounds__(256) void km_mfma(
    const unsigned short* __restrict__ Mth, const unsigned short* __restrict__ Mtl,
    const unsigned short* __restrict__ Kth, const unsigned short* __restrict__ Ktl,
    unsigned short* __restrict__ KMh, unsigned short* __restrict__ KMl) {
  __shared__ __attribute__((aligned(16))) unsigned short sm[24576];  // 48 KB
  unsigned short* MtH = sm;
  unsigned short* MtL = sm + 8192;
  unsigned short* KtH = sm + 16384;
  unsigned short* KtL = sm + 20480;
  const int tid = threadIdx.x, lane = tid & 63, w = tid >> 6;
  const int g = lane >> 4, li = lane & 15;
  const int t0 = blockIdx.x << 7;
  const int bh = blockIdx.y;
  const unsigned short* KtHb = Kth + (size_t)bh * 64 * 2048;
  const unsigned short* KtLb = Ktl + (size_t)bh * 64 * 2048;

  f32x4 acc[2][4];
#pragma unroll
  for (int mi = 0; mi < 2; ++mi)
#pragma unroll
    for (int ni = 0; ni < 4; ++ni) acc[mi][ni] = (f32x4){0.f, 0.f, 0.f, 0.f};

  for (int s0 = 0; s0 < 2048; s0 += 64) {
    __syncthreads();
    stage_tile(Mth + (size_t)t0 * 2048 + s0, 2048, MtH, 128, tid);
    stage_tile(Mtl + (size_t)t0 * 2048 + s0, 2048, MtL, 128, tid);
    stage_tile(KtHb + s0, 2048, KtH, 64, tid);
    stage_tile(KtLb + s0, 2048, KtL, 64, tid);
    asm volatile("s_waitcnt vmcnt(0)" ::: "memory");
    __syncthreads();
#pragma unroll
    for (int kk = 0; kk < 2; ++kk) {
      const int kb = (kk * 32 + 8 * g) * 2;
      bf16x8 aH[2], aL[2];
#pragma unroll
      for (int mi = 0; mi < 2; ++mi) {
        const int row = (w << 5) + (mi << 4) + li;
        aH[mi] = *(const bf16x8*)((const char*)MtH + swz(row, kb));
        aL[mi] = *(const bf16x8*)((const char*)MtL + swz(row, kb));
      }
#pragma unroll
      for (int ni = 0; ni < 4; ++ni) {
        const int row = (ni << 4) + li;
        const int off = swz(row, kb);
        const bf16x8 bH = *(const bf16x8*)((const char*)KtH + off);
        const bf16x8 bL = *(const bf16x8*)((const char*)KtL + off);
#pragma unroll
        for (int mi = 0; mi < 2; ++mi) {
          acc[mi][ni] = __builtin_amdgcn_mfma_f32_16x16x32_bf16(aH[mi], bH, acc[mi][ni], 0, 0, 0);
          acc[mi][ni] = __builtin_amdgcn_mfma_f32_16x16x32_bf16(aH[mi], bL, acc[mi][ni], 0, 0, 0);
          acc[mi][ni] = __builtin_amdgcn_mfma_f32_16x16x32_bf16(aL[mi], bH, acc[mi][ni], 0, 0, 0);
        }
      }
    }
  }
  const size_t base = (size_t)bh * 2048 * 64;
#pragma unroll
  for (int mi = 0; mi < 2; ++mi)
#pragma unroll
    for (int r = 0; r < 4; ++r) {
      const int trow = t0 + (w << 5) + (mi << 4) + (g << 2) + r;
#pragma unroll
      for (int ni = 0; ni < 4; ++ni) {
        const float x = acc[mi][ni][r];
        const unsigned short hh = f2bf(x);
        const size_t idx = base + (size_t)trow * 64 + (ni << 4) + li;
        KMh[idx] = hh;
        KMl[idx] = f2bf(x - bf2f(hh));
      }
    }
}

// ---------------------------------------------------------------------------
// attn32: block = 128 q-rows (4 waves x 32q), 32x32x16 MFMA, swapped operands.
// z fragments: col = q (lane&31), row = t -> softmax rows lane-local.
// Q B-fragments live in registers (loop-invariant). P roundtrips per-wave LDS.
// ---------------------------------------------------------------------------
__global__ __launch_bounds__(256, 3) void attn32(
    const float* __restrict__ Q, const unsigned short* __restrict__ KMh,
    const unsigned short* __restrict__ KMl, const unsigned short* __restrict__ Vt,
    float* __restrict__ Out) {
  __shared__ __attribute__((aligned(16))) unsigned short sm[20480];  // 40 KB
  unsigned short* KH = sm;          // [64 t][64 e]
  unsigned short* KL = sm + 4096;
  unsigned short* VT = sm + 8192;   // [64 d][64 t]
  const int tid = threadIdx.x, lane = tid & 63, w = tid >> 6;
  const int g2 = lane >> 5, li5 = lane & 31;
  unsigned short* PS = sm + 12288 + (w << 11);  // per-wave [32 q][64 t]

  // balanced big-first grid + XCD grouping (4 bh per XCD)
  const int bid = (int)blockIdx.x + ((int)blockIdx.y << 4);
  const int wk = ((bid & 7) << 6) | (bid >> 3);
  const int bh = wk >> 4;
  const int lt = 15 - (wk & 15);
  const int b = bh >> 3, h = bh & 7;
  const int l0 = lt << 7;
  const int qg = l0 + (w << 5) + li5;

  // Q fragments (hi/lo) in registers: B[k=e][n=q], k = 16*kk + 8*g2 + j
  bf16x8 qh[4], ql[4];
  {
    const float* qsrc = Q + (((size_t)(b * 2048 + qg) * 8 + h) << 6) + (g2 << 3);
#pragma unroll
    for (int kk = 0; kk < 4; ++kk) {
      const float4 v0 = *(const float4*)(qsrc + 16 * kk);
      const float4 v1 = *(const float4*)(qsrc + 16 * kk + 4);
      const float xs[8] = {v0.x, v0.y, v0.z, v0.w, v1.x, v1.y, v1.z, v1.w};
#pragma unroll
      for (int j = 0; j < 8; ++j) {
        const unsigned short hh = f2bf(xs[j]);
        qh[kk][j] = (short)hh;
        ql[kk][j] = (short)f2bf(xs[j] - bf2f(hh));
      }
    }
  }

  f32x16 o0 = {0,0,0,0,0,0,0,0,0,0,0,0,0,0,0,0};
  f32x16 o1 = {0,0,0,0,0,0,0,0,0,0,0,0,0,0,0,0};
  float m2 = -1e30f, lsum = 0.f;
  const float SC2 = 0.18033688011112042f;  // 0.125 * log2(e)

  const unsigned short* KHb = KMh + (size_t)bh * 2048 * 64;
  const unsigned short* KLb = KMl + (size_t)bh * 2048 * 64;
  const unsigned short* VTb = Vt + (size_t)bh * 64 * 2048;

  const int jtmax_blk = 2 * lt + 1;
  const int jtmax_w = 2 * lt + (w >> 1);

  for (int jt = 0; jt <= jtmax_blk; ++jt) {
    __syncthreads();
    stage_tile(KHb + (size_t)jt * 4096, 64, KH, 64, tid);
    stage_tile(KLb + (size_t)jt * 4096, 64, KL, 64, tid);
    stage_tile(VTb + jt * 64, 2048, VT, 64, tid);
    asm volatile("s_waitcnt vmcnt(0)" ::: "memory");
    __syncthreads();
    if (jt > jtmax_w) continue;  // fully-masked tile for this wave

    // z = KM * Q : A = KM[t][e] rows (2 t-frags), B = Q regs
    f32x16 z0 = {0,0,0,0,0,0,0,0,0,0,0,0,0,0,0,0};
    f32x16 z1 = {0,0,0,0,0,0,0,0,0,0,0,0,0,0,0,0};
#pragma unroll
    for (int kk = 0; kk < 4; ++kk) {
      const int cb = 32 * kk + 16 * g2;
      const bf16x8 a0h = *(const bf16x8*)((const char*)KH + swz(li5, cb));
      const bf16x8 a0l = *(const bf16x8*)((const char*)KL + swz(li5, cb));
      const bf16x8 a1h = *(const bf16x8*)((const char*)KH + swz(32 + li5, cb));
      const bf16x8 a1l = *(const bf16x8*)((const char*)KL + swz(32 + li5, cb));
      z0 = __builtin_amdgcn_mfma_f32_32x32x16_bf16(a0h, qh[kk], z0, 0, 0, 0);
      z0 = __builtin_amdgcn_mfma_f32_32x32x16_bf16(a0h, ql[kk], z0, 0, 0, 0);
      z0 = __builtin_amdgcn_mfma_f32_32x32x16_bf16(a0l, qh[kk], z0, 0, 0, 0);
      z1 = __builtin_amdgcn_mfma_f32_32x32x16_bf16(a1h, qh[kk], z1, 0, 0, 0);
      z1 = __builtin_amdgcn_mfma_f32_32x32x16_bf16(a1h, ql[kk], z1, 0, 0, 0);
      z1 = __builtin_amdgcn_mfma_f32_32x32x16_bf16(a1l, qh[kk], z1, 0, 0, 0);
    }

    // scale (base-2 domain) + causal mask; t_loc = tf*32 + 4g2 + 8*(r>>2) + (r&3)
    const bool needmask = (jt * 64 + 63 > l0 + (w << 5));
    const int thr = qg - jt * 64;  // mask if t_loc > thr
    if (needmask) {
#pragma unroll
      for (int r = 0; r < 16; ++r) {
        const int tl = (g2 << 2) + ((r >> 2) << 3) + (r & 3);
        z0[r] = (tl > thr) ? -1e30f : z0[r] * SC2;
        z1[r] = (tl + 32 > thr) ? -1e30f : z1[r] * SC2;
      }
    } else {
#pragma unroll
      for (int r = 0; r < 16; ++r) { z0[r] *= SC2; z1[r] *= SC2; }
    }

    // online softmax: rows lane-local, one cross-lane hop (g2 halves)
    float mx = fmaxf(z0[0], z1[0]);
#pragma unroll
    for (int r = 1; r < 16; ++r) mx = fmaxf(mx, fmaxf(z0[r], z1[r]));
    mx = fmaxf(mx, __shfl_xor(mx, 32));
    const float m2n = fmaxf(m2, mx);
    const float fs = exp2f(m2 - m2n);
    m2 = m2n;
    float pv0[16], pv1[16];
    float rs = 0.f;
#pragma unroll
    for (int r = 0; r < 16; ++r) {
      pv0[r] = exp2f(z0[r] - m2n);
      pv1[r] = exp2f(z1[r] - m2n);
      rs += pv0[r] + pv1[r];
    }
    rs += __shfl_xor(rs, 32);
    lsum = lsum * fs + rs;
#pragma unroll
    for (int r = 0; r < 16; ++r) { o0[r] *= fs; o1[r] *= fs; }

    // P -> per-wave LDS (swizzled): row q=li5, byte = 2*t
#pragma unroll
    for (int r2 = 0; r2 < 4; ++r2) {
      const int bb = (r2 << 4) + (g2 << 3);
      uint a0 = (uint)f2bf(pv0[4 * r2]) | ((uint)f2bf(pv0[4 * r2 + 1]) << 16);
      uint a1 = (uint)f2bf(pv0[4 * r2 + 2]) | ((uint)f2bf(pv0[4 * r2 + 3]) << 16);
      *(uint2*)((char*)PS + swz(li5, bb)) = make_uint2(a0, a1);
      uint b0 = (uint)f2bf(pv1[4 * r2]) | ((uint)f2bf(pv1[4 * r2 + 1]) << 16);
      uint b1 = (uint)f2bf(pv1[4 * r2 + 2]) | ((uint)f2bf(pv1[4 * r2 + 3]) << 16);
      *(uint2*)((char*)PS + swz(li5, 64 + bb)) = make_uint2(b0, b1);
    }

    // O += V^T * P : A = VT[d][t] rows (2 d-frags), B = P from per-wave LDS
#pragma unroll
    for (int kk = 0; kk < 4; ++kk) {
      const int cb = 32 * kk + 16 * g2;
      const bf16x8 pf = *(const bf16x8*)((const char*)PS + swz(li5, cb));
      const bf16x8 v0f = *(const bf16x8*)((const char*)VT + swz(li5, cb));
      const bf16x8 v1f = *(const bf16x8*)((const char*)VT + swz(32 + li5, cb));
      o0 = __builtin_amdgcn_mfma_f32_32x32x16_bf16(v0f, pf, o0, 0, 0, 0);
      o1 = __builtin_amdgcn_mfma_f32_32x32x16_bf16(v1f, pf, o1, 0, 0, 0);
    }
  }

  // epilogue: O[b, qg, h, d], d = df*32 + 4*g2 + 8*r2 + rr
  const float inv = 1.f / lsum;
  float* ob = Out + (((size_t)(b * 2048 + qg) * 8 + h) << 6);
#pragma unroll
  for (int r2 = 0; r2 < 4; ++r2) {
    const int doff = (g2 << 2) + (r2 << 3);
    float4 s0 = make_float4(o0[4 * r2] * inv, o0[4 * r2 + 1] * inv,
                            o0[4 * r2 + 2] * inv, o0[4 * r2 + 3] * inv);
    *(float4*)(ob + doff) = s0;
    float4 s1 = make_float4(o1[4 * r2] * inv, o1[4 * r2 + 1] * inv,
                            o1[4 * r2 + 2] * inv, o1[4 * r2 + 3] * inv);
    *(float4*)(ob + 32 + doff) = s1;
  }
}

extern "C" void kernel_launch(void* const* d_in, const int* in_sizes, int n_in,
                              void* d_out, int out_size, void* d_ws, size_t ws_size,
                              hipStream_t stream) {
  const float* Q = (const float*)d_in[0];
  const float* K = (const float*)d_in[1];
  const float* V = (const float*)d_in[2];
  const float* M = (const float*)d_in[3];
  float* Out = (float*)d_out;
  char* ws = (char*)d_ws;
  const size_t MB = 1u << 20;
  unsigned short* Mth = (unsigned short*)(ws);            // [2048 t][2048 s]
  unsigned short* Mtl = (unsigned short*)(ws + 8 * MB);
  unsigned short* Kth = (unsigned short*)(ws + 16 * MB);  // [32 bh][64 e][2048 s]
  unsigned short* Ktl = (unsigned short*)(ws + 24 * MB);
  unsigned short* Vts = (unsigned short*)(ws + 32 * MB);  // [32 bh][64 d][2048 s]
  unsigned short* KMh = (unsigned short*)(ws + 40 * MB);  // [32 bh][2048 t][64 e]
  unsigned short* KMl = (unsigned short*)(ws + 48 * MB);

  prep_m<<<dim3(32, 32), 256, 0, stream>>>(M, Mth, Mtl);
  prep_kv<<<dim3(32, 32), 256, 0, stream>>>(K, Kth, Ktl, 1);
  prep_kv<<<dim3(32, 32), 256, 0, stream>>>(V, Vts, (unsigned short*)nullptr, 0);
  km_mfma<<<dim3(16, 32), 256, 0, stream>>>(Mth, Mtl, Kth, Ktl, KMh, KMl);
  attn32<<<dim3(16, 32), 256, 0, stream>>>(Q, KMh, KMl, Vts, Out);
}

// Round 4
// 154.779 us; speedup vs baseline: 4.8248x; 1.1622x over previous
//
#include <hip/hip_runtime.h>

// B=4, L=S=2048, H=8, E=D=64.  KM[bh][t][e] = sum_s K[b,s,h,e]*M[s,t] (split
// bf16 hi/lo), then flash attention z = Q*KM/8, causal, online softmax.
// Round 4: attn gets (a) complementary block pairing (lt + (15-lt) per CU,
// 4 bh per XCD), (b) double-buffered K/V staging with raw s_barrier + counted
// vmcnt drain (prefetch overlaps compute), (c) setprio around MFMA clusters.

typedef short bf16x8 __attribute__((ext_vector_type(8)));
typedef float f32x4 __attribute__((ext_vector_type(4)));
typedef float f32x16 __attribute__((ext_vector_type(16)));
typedef unsigned short u16x8 __attribute__((ext_vector_type(8)));

typedef __attribute__((address_space(1))) const void gvoid;
typedef __attribute__((address_space(3))) void lvoid;

__device__ __forceinline__ unsigned short f2bf(float x) {
  unsigned int u = __float_as_uint(x);
  u += 0x7FFFu + ((u >> 16) & 1u);
  return (unsigned short)(u >> 16);
}
__device__ __forceinline__ float bf2f(unsigned short h) {
  return __uint_as_float(((unsigned int)h) << 16);
}

__device__ __forceinline__ void gload16(const unsigned short* g, unsigned short* l) {
  __builtin_amdgcn_global_load_lds((gvoid*)g, (lvoid*)l, 16, 0, 0);
}

// Stage a [rows][64 bf16] tile (row stride 128B in LDS) from global rows of
// stride gstride. LDS dest LINEAR (global_load_lds rule); XOR swizzle
// byte^=((row&7)<<4) realized by pre-swizzling the global SOURCE address.
__device__ __forceinline__ void stage_tile(const unsigned short* __restrict__ g,
                                           int gstride, unsigned short* l,
                                           int rows, int tid) {
  const int lane = tid & 63, w = tid >> 6;
  const int nch = rows << 3;  // 16B chunks
  for (int c0 = (w << 6); c0 < nch; c0 += 256) {
    const int c = c0 + lane;
    const int row = c >> 3;
    const int bir = (c & 7) << 4;
    const int sb = bir ^ ((row & 7) << 4);
    gload16(g + (size_t)row * gstride + (sb >> 1), l + (size_t)c0 * 8);
  }
}

// swizzled byte offset inside a [*][64 bf16] tile
__device__ __forceinline__ int swz(int row, int byteInRow) {
  return row * 128 + (byteInRow ^ ((row & 7) << 4));
}

// ---------------------------------------------------------------------------
// prep_m: Mt_hi/lo[t][s] = split(M[s][t])
// ---------------------------------------------------------------------------
__global__ __launch_bounds__(256) void prep_m(const float* __restrict__ M,
                                              unsigned short* __restrict__ Mh,
                                              unsigned short* __restrict__ Ml) {
  __shared__ float Ts[64][68];
  const int s0 = blockIdx.x << 6, t0 = blockIdx.y << 6;
  const int tid = threadIdx.x, r = tid >> 2, c0 = (tid & 3) << 4;
  const float* src = M + (size_t)(s0 + r) * 2048 + t0 + c0;
#pragma unroll
  for (int j = 0; j < 4; ++j)
    *(float4*)&Ts[r][c0 + 4 * j] = *(const float4*)(src + 4 * j);
  __syncthreads();
  u16x8 h0, h1, l0v, l1v;
#pragma unroll
  for (int j = 0; j < 8; ++j) {
    float x = Ts[c0 + j][r];
    unsigned short hh = f2bf(x);
    h0[j] = hh; l0v[j] = f2bf(x - bf2f(hh));
  }
#pragma unroll
  for (int j = 8; j < 16; ++j) {
    float x = Ts[c0 + j][r];
    unsigned short hh = f2bf(x);
    h1[j - 8] = hh; l1v[j - 8] = f2bf(x - bf2f(hh));
  }
  const size_t o = (size_t)(t0 + r) * 2048 + s0 + c0;
  *(u16x8*)(Mh + o) = h0; *(u16x8*)(Mh + o + 8) = h1;
  *(u16x8*)(Ml + o) = l0v; *(u16x8*)(Ml + o + 8) = l1v;
}

// ---------------------------------------------------------------------------
// prep_kv: Dst[bh][e][s] = split(src[b,s,h,e]); has_lo=0 -> single plane (V)
// ---------------------------------------------------------------------------
__global__ __launch_bounds__(256) void prep_kv(const float* __restrict__ src4d,
                                               unsigned short* __restrict__ Dh,
                                               unsigned short* __restrict__ Dl,
                                               int has_lo) {
  __shared__ float Ts[64][68];
  const int s0 = blockIdx.x << 6, bh = blockIdx.y;
  const int b = bh >> 3, h = bh & 7;
  const int tid = threadIdx.x, r = tid >> 2, c0 = (tid & 3) << 4;
  const float* src = src4d + ((size_t)(b * 2048 + s0 + r) * 8 + h) * 64 + c0;
#pragma unroll
  for (int j = 0; j < 4; ++j)
    *(float4*)&Ts[r][c0 + 4 * j] = *(const float4*)(src + 4 * j);
  __syncthreads();
  u16x8 h0, h1, l0v, l1v;
#pragma unroll
  for (int j = 0; j < 8; ++j) {
    float x = Ts[c0 + j][r];
    unsigned short hh = f2bf(x);
    h0[j] = hh; l0v[j] = f2bf(x - bf2f(hh));
  }
#pragma unroll
  for (int j = 8; j < 16; ++j) {
    float x = Ts[c0 + j][r];
    unsigned short hh = f2bf(x);
    h1[j - 8] = hh; l1v[j - 8] = f2bf(x - bf2f(hh));
  }
  const size_t o = ((size_t)bh * 64 + r) * 2048 + s0 + c0;
  *(u16x8*)(Dh + o) = h0; *(u16x8*)(Dh + o + 8) = h1;
  if (has_lo) { *(u16x8*)(Dl + o) = l0v; *(u16x8*)(Dl + o + 8) = l1v; }
}

// ---------------------------------------------------------------------------
// km_mfma: KM[bh][t][e] (hi/lo) = sum_s M[s][t]*K[s][e]  (unchanged, proven)
// ---------------------------------------------------------------------------
__global__ __launch_bounds__(256) void km_mfma(
    const unsigned short* __restrict__ Mth, const unsigned short* __restrict__ Mtl,
    const unsigned short* __restrict__ Kth, const unsigned short* __restrict__ Ktl,
    unsigned short* __restrict__ KMh, unsigned short* __restrict__ KMl) {
  __shared__ __attribute__((aligned(16))) unsigned short sm[24576];  // 48 KB
  unsigned short* MtH = sm;
  unsigned short* MtL = sm + 8192;
  unsigned short* KtH = sm + 16384;
  unsigned short* KtL = sm + 20480;
  const int tid = threadIdx.x, lane = tid & 63, w = tid >> 6;
  const int g = lane >> 4, li = lane & 15;
  const int t0 = blockIdx.x << 7;
  const int bh = blockIdx.y;
  const unsigned short* KtHb = Kth + (size_t)bh * 64 * 2048;
  const unsigned short* KtLb = Ktl + (size_t)bh * 64 * 2048;

  f32x4 acc[2][4];
#pragma unroll
  for (int mi = 0; mi < 2; ++mi)
#pragma unroll
    for (int ni = 0; ni < 4; ++ni) acc[mi][ni] = (f32x4){0.f, 0.f, 0.f, 0.f};

  for (int s0 = 0; s0 < 2048; s0 += 64) {
    __syncthreads();
    stage_tile(Mth + (size_t)t0 * 2048 + s0, 2048, MtH, 128, tid);
    stage_tile(Mtl + (size_t)t0 * 2048 + s0, 2048, MtL, 128, tid);
    stage_tile(KtHb + s0, 2048, KtH, 64, tid);
    stage_tile(KtLb + s0, 2048, KtL, 64, tid);
    asm volatile("s_waitcnt vmcnt(0)" ::: "memory");
    __syncthreads();
#pragma unroll
    for (int kk = 0; kk < 2; ++kk) {
      const int kb = (kk * 32 + 8 * g) * 2;
      bf16x8 aH[2], aL[2];
#pragma unroll
      for (int mi = 0; mi < 2; ++mi) {
        const int row = (w << 5) + (mi << 4) + li;
        aH[mi] = *(const bf16x8*)((const char*)MtH + swz(row, kb));
        aL[mi] = *(const bf16x8*)((const char*)MtL + swz(row, kb));
      }
#pragma unroll
      for (int ni = 0; ni < 4; ++ni) {
        const int row = (ni << 4) + li;
        const int off = swz(row, kb);
        const bf16x8 bH = *(const bf16x8*)((const char*)KtH + off);
        const bf16x8 bL = *(const bf16x8*)((const char*)KtL + off);
#pragma unroll
        for (int mi = 0; mi < 2; ++mi) {
          acc[mi][ni] = __builtin_amdgcn_mfma_f32_16x16x32_bf16(aH[mi], bH, acc[mi][ni], 0, 0, 0);
          acc[mi][ni] = __builtin_amdgcn_mfma_f32_16x16x32_bf16(aH[mi], bL, acc[mi][ni], 0, 0, 0);
          acc[mi][ni] = __builtin_amdgcn_mfma_f32_16x16x32_bf16(aL[mi], bH, acc[mi][ni], 0, 0, 0);
        }
      }
    }
  }
  const size_t base = (size_t)bh * 2048 * 64;
#pragma unroll
  for (int mi = 0; mi < 2; ++mi)
#pragma unroll
    for (int r = 0; r < 4; ++r) {
      const int trow = t0 + (w << 5) + (mi << 4) + (g << 2) + r;
#pragma unroll
      for (int ni = 0; ni < 4; ++ni) {
        const float x = acc[mi][ni][r];
        const unsigned short hh = f2bf(x);
        const size_t idx = base + (size_t)trow * 64 + (ni << 4) + li;
        KMh[idx] = hh;
        KMl[idx] = f2bf(x - bf2f(hh));
      }
    }
}

// ---------------------------------------------------------------------------
// attn32: block = 128 q-rows (4 waves x 32q), 32x32x16 MFMA, swapped operands.
// Double-buffered K/V staging; one raw s_barrier per tile (counted drain).
// Grid: 512 1-D blocks; bid -> (bh, lt) with complementary CU pairing:
// x=bid&7 (XCD), r=bid>>3, bh=4x+(r&3), m=r>>2, lt = m<8 ? 15-m : m-8.
// Paired blocks (r, r+32) land on the same CU -> lt sums to 15 (36 tiles).
// ---------------------------------------------------------------------------
__global__ __launch_bounds__(256, 2) void attn32(
    const float* __restrict__ Q, const unsigned short* __restrict__ KMh,
    const unsigned short* __restrict__ KMl, const unsigned short* __restrict__ Vt,
    float* __restrict__ Out) {
  // LDS: 2 staging buffers x {KH 8KB, KL 8KB, VT 8KB} + 4x4KB per-wave P = 64KB
  __shared__ __attribute__((aligned(16))) unsigned short sm[32768];
  const int tid = threadIdx.x, lane = tid & 63, w = tid >> 6;
  const int g2 = lane >> 5, li5 = lane & 31;
  unsigned short* PS = sm + 24576 + (w << 11);  // per-wave [32 q][64 t]

  const int bid = (int)blockIdx.x;
  const int x = bid & 7;
  const int r = bid >> 3;
  const int m = r >> 2;
  const int bh = (x << 2) | (r & 3);
  const int lt = (m < 8) ? (15 - m) : (m - 8);
  const int b = bh >> 3, h = bh & 7;
  const int l0 = lt << 7;
  const int qg = l0 + (w << 5) + li5;

  // Q fragments (hi/lo) in registers: B[k=e][n=q], k = 16*kk + 8*g2 + j
  bf16x8 qh[4], ql[4];
  {
    const float* qsrc = Q + (((size_t)(b * 2048 + qg) * 8 + h) << 6) + (g2 << 3);
#pragma unroll
    for (int kk = 0; kk < 4; ++kk) {
      const float4 v0 = *(const float4*)(qsrc + 16 * kk);
      const float4 v1 = *(const float4*)(qsrc + 16 * kk + 4);
      const float xs[8] = {v0.x, v0.y, v0.z, v0.w, v1.x, v1.y, v1.z, v1.w};
#pragma unroll
      for (int j = 0; j < 8; ++j) {
        const unsigned short hh = f2bf(xs[j]);
        qh[kk][j] = (short)hh;
        ql[kk][j] = (short)f2bf(xs[j] - bf2f(hh));
      }
    }
  }

  f32x16 o0 = {0,0,0,0,0,0,0,0,0,0,0,0,0,0,0,0};
  f32x16 o1 = {0,0,0,0,0,0,0,0,0,0,0,0,0,0,0,0};
  float m2 = -1e30f, lsum = 0.f;
  const float SC2 = 0.18033688011112042f;  // 0.125 * log2(e)

  const unsigned short* KHb = KMh + (size_t)bh * 2048 * 64;
  const unsigned short* KLb = KMl + (size_t)bh * 2048 * 64;
  const unsigned short* VTb = Vt + (size_t)bh * 64 * 2048;

  const int jtmax_blk = 2 * lt + 1;
  const int jtmax_w = 2 * lt + (w >> 1);

  // prologue: stage tile 0 into buffer 0
  {
    unsigned short* s0b = sm;
    stage_tile(KHb, 64, s0b, 64, tid);
    stage_tile(KLb, 64, s0b + 4096, 64, tid);
    stage_tile(VTb, 2048, s0b + 8192, 64, tid);
  }
  asm volatile("s_waitcnt vmcnt(0)" ::: "memory");
  __builtin_amdgcn_s_barrier();
  __builtin_amdgcn_sched_barrier(0);

  for (int jt = 0; jt <= jtmax_blk; ++jt) {
    const int cur = jt & 1;
    // prefetch next tile into the other buffer (overlaps this tile's compute)
    if (jt < jtmax_blk) {
      unsigned short* nb = sm + (cur ^ 1) * 12288;
      stage_tile(KHb + (size_t)(jt + 1) * 4096, 64, nb, 64, tid);
      stage_tile(KLb + (size_t)(jt + 1) * 4096, 64, nb + 4096, 64, tid);
      stage_tile(VTb + (jt + 1) * 64, 2048, nb + 8192, 64, tid);
    }

    if (jt <= jtmax_w) {
      const unsigned short* KH = sm + cur * 12288;
      const unsigned short* KL = KH + 4096;
      const unsigned short* VT = KH + 8192;

      // z = KM * Q : A = KM[t][e] rows (2 t-frags), B = Q regs
      f32x16 z0 = {0,0,0,0,0,0,0,0,0,0,0,0,0,0,0,0};
      f32x16 z1 = {0,0,0,0,0,0,0,0,0,0,0,0,0,0,0,0};
      __builtin_amdgcn_s_setprio(1);
#pragma unroll
      for (int kk = 0; kk < 4; ++kk) {
        const int cb = 32 * kk + 16 * g2;
        const bf16x8 a0h = *(const bf16x8*)((const char*)KH + swz(li5, cb));
        const bf16x8 a0l = *(const bf16x8*)((const char*)KL + swz(li5, cb));
        const bf16x8 a1h = *(const bf16x8*)((const char*)KH + swz(32 + li5, cb));
        const bf16x8 a1l = *(const bf16x8*)((const char*)KL + swz(32 + li5, cb));
        z0 = __builtin_amdgcn_mfma_f32_32x32x16_bf16(a0h, qh[kk], z0, 0, 0, 0);
        z0 = __builtin_amdgcn_mfma_f32_32x32x16_bf16(a0h, ql[kk], z0, 0, 0, 0);
        z0 = __builtin_amdgcn_mfma_f32_32x32x16_bf16(a0l, qh[kk], z0, 0, 0, 0);
        z1 = __builtin_amdgcn_mfma_f32_32x32x16_bf16(a1h, qh[kk], z1, 0, 0, 0);
        z1 = __builtin_amdgcn_mfma_f32_32x32x16_bf16(a1h, ql[kk], z1, 0, 0, 0);
        z1 = __builtin_amdgcn_mfma_f32_32x32x16_bf16(a1l, qh[kk], z1, 0, 0, 0);
      }
      __builtin_amdgcn_s_setprio(0);

      // scale (base-2) + causal mask; t_loc = tf*32 + 4g2 + 8*(r>>2) + (r&3)
      const bool needmask = (jt * 64 + 63 > l0 + (w << 5));
      const int thr = qg - jt * 64;  // mask if t_loc > thr
      if (needmask) {
#pragma unroll
        for (int rr = 0; rr < 16; ++rr) {
          const int tl = (g2 << 2) + ((rr >> 2) << 3) + (rr & 3);
          z0[rr] = (tl > thr) ? -1e30f : z0[rr] * SC2;
          z1[rr] = (tl + 32 > thr) ? -1e30f : z1[rr] * SC2;
        }
      } else {
#pragma unroll
        for (int rr = 0; rr < 16; ++rr) { z0[rr] *= SC2; z1[rr] *= SC2; }
      }

      // online softmax, tree reductions (rows lane-local; one cross-lane hop)
      float t16[16];
#pragma unroll
      for (int rr = 0; rr < 16; ++rr) t16[rr] = fmaxf(z0[rr], z1[rr]);
#pragma unroll
      for (int s = 8; s; s >>= 1)
#pragma unroll
        for (int rr = 0; rr < 8; ++rr)
          if (rr < s) t16[rr] = fmaxf(t16[rr], t16[rr + s]);
      float mx = fmaxf(t16[0], __shfl_xor(t16[0], 32));
      const float m2n = fmaxf(m2, mx);
      const float fs = exp2f(m2 - m2n);
      m2 = m2n;
      float pv0[16], pv1[16];
#pragma unroll
      for (int rr = 0; rr < 16; ++rr) {
        pv0[rr] = exp2f(z0[rr] - m2n);
        pv1[rr] = exp2f(z1[rr] - m2n);
      }
      float s16[16];
#pragma unroll
      for (int rr = 0; rr < 16; ++rr) s16[rr] = pv0[rr] + pv1[rr];
#pragma unroll
      for (int s = 8; s; s >>= 1)
#pragma unroll
        for (int rr = 0; rr < 8; ++rr)
          if (rr < s) s16[rr] += s16[rr + s];
      float rs = s16[0] + __shfl_xor(s16[0], 32);
      lsum = lsum * fs + rs;
#pragma unroll
      for (int rr = 0; rr < 16; ++rr) { o0[rr] *= fs; o1[rr] *= fs; }

      // P -> per-wave LDS (swizzled): row q=li5, byte = 2*t
#pragma unroll
      for (int r2 = 0; r2 < 4; ++r2) {
        const int bb = (r2 << 4) + (g2 << 3);
        uint a0 = (uint)f2bf(pv0[4 * r2]) | ((uint)f2bf(pv0[4 * r2 + 1]) << 16);
        uint a1 = (uint)f2bf(pv0[4 * r2 + 2]) | ((uint)f2bf(pv0[4 * r2 + 3]) << 16);
        *(uint2*)((char*)PS + swz(li5, bb)) = make_uint2(a0, a1);
        uint b0 = (uint)f2bf(pv1[4 * r2]) | ((uint)f2bf(pv1[4 * r2 + 1]) << 16);
        uint b1 = (uint)f2bf(pv1[4 * r2 + 2]) | ((uint)f2bf(pv1[4 * r2 + 3]) << 16);
        *(uint2*)((char*)PS + swz(li5, 64 + bb)) = make_uint2(b0, b1);
      }

      // O += V^T * P : A = VT[d][t] rows (2 d-frags), B = P per-wave LDS
      __builtin_amdgcn_s_setprio(1);
#pragma unroll
      for (int kk = 0; kk < 4; ++kk) {
        const int cb = 32 * kk + 16 * g2;
        const bf16x8 pf = *(const bf16x8*)((const char*)PS + swz(li5, cb));
        const bf16x8 v0f = *(const bf16x8*)((const char*)VT + swz(li5, cb));
        const bf16x8 v1f = *(const bf16x8*)((const char*)VT + swz(32 + li5, cb));
        o0 = __builtin_amdgcn_mfma_f32_32x32x16_bf16(v0f, pf, o0, 0, 0, 0);
        o1 = __builtin_amdgcn_mfma_f32_32x32x16_bf16(v1f, pf, o1, 0, 0, 0);
      }
      __builtin_amdgcn_s_setprio(0);
    }

    // end-of-tile: drain this tile's prefetch, then block-wide barrier.
    asm volatile("s_waitcnt vmcnt(0)" ::: "memory");
    __builtin_amdgcn_s_barrier();
    __builtin_amdgcn_sched_barrier(0);
  }

  // epilogue: O[b, qg, h, d], d = df*32 + 4*g2 + 8*r2 + rr
  const float inv = 1.f / lsum;
  float* ob = Out + (((size_t)(b * 2048 + qg) * 8 + h) << 6);
#pragma unroll
  for (int r2 = 0; r2 < 4; ++r2) {
    const int doff = (g2 << 2) + (r2 << 3);
    float4 s0 = make_float4(o0[4 * r2] * inv, o0[4 * r2 + 1] * inv,
                            o0[4 * r2 + 2] * inv, o0[4 * r2 + 3] * inv);
    *(float4*)(ob + doff) = s0;
    float4 s1 = make_float4(o1[4 * r2] * inv, o1[4 * r2 + 1] * inv,
                            o1[4 * r2 + 2] * inv, o1[4 * r2 + 3] * inv);
    *(float4*)(ob + 32 + doff) = s1;
  }
}

extern "C" void kernel_launch(void* const* d_in, const int* in_sizes, int n_in,
                              void* d_out, int out_size, void* d_ws, size_t ws_size,
                              hipStream_t stream) {
  const float* Q = (const float*)d_in[0];
  const float* K = (const float*)d_in[1];
  const float* V = (const float*)d_in[2];
  const float* M = (const float*)d_in[3];
  float* Out = (float*)d_out;
  char* ws = (char*)d_ws;
  const size_t MB = 1u << 20;
  unsigned short* Mth = (unsigned short*)(ws);            // [2048 t][2048 s]
  unsigned short* Mtl = (unsigned short*)(ws + 8 * MB);
  unsigned short* Kth = (unsigned short*)(ws + 16 * MB);  // [32 bh][64 e][2048 s]
  unsigned short* Ktl = (unsigned short*)(ws + 24 * MB);
  unsigned short* Vts = (unsigned short*)(ws + 32 * MB);  // [32 bh][64 d][2048 s]
  unsigned short* KMh = (unsigned short*)(ws + 40 * MB);  // [32 bh][2048 t][64 e]
  unsigned short* KMl = (unsigned short*)(ws + 48 * MB);

  prep_m<<<dim3(32, 32), 256, 0, stream>>>(M, Mth, Mtl);
  prep_kv<<<dim3(32, 32), 256, 0, stream>>>(K, Kth, Ktl, 1);
  prep_kv<<<dim3(32, 32), 256, 0, stream>>>(V, Vts, (unsigned short*)nullptr, 0);
  km_mfma<<<dim3(16, 32), 256, 0, stream>>>(Mth, Mtl, Kth, Ktl, KMh, KMl);
  attn32<<<dim3(512), 256, 0, stream>>>(Q, KMh, KMl, Vts, Out);
}

// Round 5
// 147.511 us; speedup vs baseline: 5.0625x; 1.0493x over previous
//
#include <hip/hip_runtime.h>

// B=4, L=S=2048, H=8, E=D=64.  KM[bh][t][e] = sum_s K[b,s,h,e]*M[s,t] (split
// bf16 hi/lo), then flash attention z = Q*KM/8, causal, online softmax.
// Round 5: attn P-fragments built in-register (cvt_pk_bf16 + permlane32_swap,
// no LDS roundtrip), lsum via ones-MFMA, defer-max rescale (THR=11 in log2),
// softmax scale folded into Q load. LDS/block 64->48KB, reads 28->24 b128.

typedef short bf16x8 __attribute__((ext_vector_type(8)));
typedef float f32x4 __attribute__((ext_vector_type(4)));
typedef float f32x16 __attribute__((ext_vector_type(16)));
typedef unsigned short u16x8 __attribute__((ext_vector_type(8)));
typedef unsigned int u32x4 __attribute__((ext_vector_type(4)));

typedef __attribute__((address_space(1))) const void gvoid;
typedef __attribute__((address_space(3))) void lvoid;

__device__ __forceinline__ unsigned short f2bf(float x) {
  unsigned int u = __float_as_uint(x);
  u += 0x7FFFu + ((u >> 16) & 1u);
  return (unsigned short)(u >> 16);
}
__device__ __forceinline__ float bf2f(unsigned short h) {
  return __uint_as_float(((unsigned int)h) << 16);
}
// pack two f32 -> (bf16(hi)<<16)|bf16(lo)
__device__ __forceinline__ unsigned int cvtpk(float lo, float hi) {
  unsigned int r;
  asm("v_cvt_pk_bf16_f32 %0, %1, %2" : "=v"(r) : "v"(lo), "v"(hi));
  return r;
}

__device__ __forceinline__ void gload16(const unsigned short* g, unsigned short* l) {
  __builtin_amdgcn_global_load_lds((gvoid*)g, (lvoid*)l, 16, 0, 0);
}

// Stage a [rows][64 bf16] tile (row stride 128B in LDS) from global rows of
// stride gstride. LDS dest LINEAR (global_load_lds rule); XOR swizzle
// byte^=((row&7)<<4) realized by pre-swizzling the global SOURCE address.
__device__ __forceinline__ void stage_tile(const unsigned short* __restrict__ g,
                                           int gstride, unsigned short* l,
                                           int rows, int tid) {
  const int lane = tid & 63, w = tid >> 6;
  const int nch = rows << 3;  // 16B chunks
  for (int c0 = (w << 6); c0 < nch; c0 += 256) {
    const int c = c0 + lane;
    const int row = c >> 3;
    const int bir = (c & 7) << 4;
    const int sb = bir ^ ((row & 7) << 4);
    gload16(g + (size_t)row * gstride + (sb >> 1), l + (size_t)c0 * 8);
  }
}

// swizzled byte offset inside a [*][64 bf16] tile
__device__ __forceinline__ int swz(int row, int byteInRow) {
  return row * 128 + (byteInRow ^ ((row & 7) << 4));
}

// ---------------------------------------------------------------------------
// prep_m: Mt_hi/lo[t][s] = split(M[s][t])
// ---------------------------------------------------------------------------
__global__ __launch_bounds__(256) void prep_m(const float* __restrict__ M,
                                              unsigned short* __restrict__ Mh,
                                              unsigned short* __restrict__ Ml) {
  __shared__ float Ts[64][68];
  const int s0 = blockIdx.x << 6, t0 = blockIdx.y << 6;
  const int tid = threadIdx.x, r = tid >> 2, c0 = (tid & 3) << 4;
  const float* src = M + (size_t)(s0 + r) * 2048 + t0 + c0;
#pragma unroll
  for (int j = 0; j < 4; ++j)
    *(float4*)&Ts[r][c0 + 4 * j] = *(const float4*)(src + 4 * j);
  __syncthreads();
  u16x8 h0, h1, l0v, l1v;
#pragma unroll
  for (int j = 0; j < 8; ++j) {
    float x = Ts[c0 + j][r];
    unsigned short hh = f2bf(x);
    h0[j] = hh; l0v[j] = f2bf(x - bf2f(hh));
  }
#pragma unroll
  for (int j = 8; j < 16; ++j) {
    float x = Ts[c0 + j][r];
    unsigned short hh = f2bf(x);
    h1[j - 8] = hh; l1v[j - 8] = f2bf(x - bf2f(hh));
  }
  const size_t o = (size_t)(t0 + r) * 2048 + s0 + c0;
  *(u16x8*)(Mh + o) = h0; *(u16x8*)(Mh + o + 8) = h1;
  *(u16x8*)(Ml + o) = l0v; *(u16x8*)(Ml + o + 8) = l1v;
}

// ---------------------------------------------------------------------------
// prep_kv: Dst[bh][e][s] = split(src[b,s,h,e]); has_lo=0 -> single plane (V)
// ---------------------------------------------------------------------------
__global__ __launch_bounds__(256) void prep_kv(const float* __restrict__ src4d,
                                               unsigned short* __restrict__ Dh,
                                               unsigned short* __restrict__ Dl,
                                               int has_lo) {
  __shared__ float Ts[64][68];
  const int s0 = blockIdx.x << 6, bh = blockIdx.y;
  const int b = bh >> 3, h = bh & 7;
  const int tid = threadIdx.x, r = tid >> 2, c0 = (tid & 3) << 4;
  const float* src = src4d + ((size_t)(b * 2048 + s0 + r) * 8 + h) * 64 + c0;
#pragma unroll
  for (int j = 0; j < 4; ++j)
    *(float4*)&Ts[r][c0 + 4 * j] = *(const float4*)(src + 4 * j);
  __syncthreads();
  u16x8 h0, h1, l0v, l1v;
#pragma unroll
  for (int j = 0; j < 8; ++j) {
    float x = Ts[c0 + j][r];
    unsigned short hh = f2bf(x);
    h0[j] = hh; l0v[j] = f2bf(x - bf2f(hh));
  }
#pragma unroll
  for (int j = 8; j < 16; ++j) {
    float x = Ts[c0 + j][r];
    unsigned short hh = f2bf(x);
    h1[j - 8] = hh; l1v[j - 8] = f2bf(x - bf2f(hh));
  }
  const size_t o = ((size_t)bh * 64 + r) * 2048 + s0 + c0;
  *(u16x8*)(Dh + o) = h0; *(u16x8*)(Dh + o + 8) = h1;
  if (has_lo) { *(u16x8*)(Dl + o) = l0v; *(u16x8*)(Dl + o + 8) = l1v; }
}

// ---------------------------------------------------------------------------
// km_mfma: KM[bh][t][e] (hi/lo) = sum_s M[s][t]*K[s][e]  (unchanged, proven)
// ---------------------------------------------------------------------------
__global__ __launch_bounds__(256) void km_mfma(
    const unsigned short* __restrict__ Mth, const unsigned short* __restrict__ Mtl,
    const unsigned short* __restrict__ Kth, const unsigned short* __restrict__ Ktl,
    unsigned short* __restrict__ KMh, unsigned short* __restrict__ KMl) {
  __shared__ __attribute__((aligned(16))) unsigned short sm[24576];  // 48 KB
  unsigned short* MtH = sm;
  unsigned short* MtL = sm + 8192;
  unsigned short* KtH = sm + 16384;
  unsigned short* KtL = sm + 20480;
  const int tid = threadIdx.x, lane = tid & 63, w = tid >> 6;
  const int g = lane >> 4, li = lane & 15;
  const int t0 = blockIdx.x << 7;
  const int bh = blockIdx.y;
  const unsigned short* KtHb = Kth + (size_t)bh * 64 * 2048;
  const unsigned short* KtLb = Ktl + (size_t)bh * 64 * 2048;

  f32x4 acc[2][4];
#pragma unroll
  for (int mi = 0; mi < 2; ++mi)
#pragma unroll
    for (int ni = 0; ni < 4; ++ni) acc[mi][ni] = (f32x4){0.f, 0.f, 0.f, 0.f};

  for (int s0 = 0; s0 < 2048; s0 += 64) {
    __syncthreads();
    stage_tile(Mth + (size_t)t0 * 2048 + s0, 2048, MtH, 128, tid);
    stage_tile(Mtl + (size_t)t0 * 2048 + s0, 2048, MtL, 128, tid);
    stage_tile(KtHb + s0, 2048, KtH, 64, tid);
    stage_tile(KtLb + s0, 2048, KtL, 64, tid);
    asm volatile("s_waitcnt vmcnt(0)" ::: "memory");
    __syncthreads();
#pragma unroll
    for (int kk = 0; kk < 2; ++kk) {
      const int kb = (kk * 32 + 8 * g) * 2;
      bf16x8 aH[2], aL[2];
#pragma unroll
      for (int mi = 0; mi < 2; ++mi) {
        const int row = (w << 5) + (mi << 4) + li;
        aH[mi] = *(const bf16x8*)((const char*)MtH + swz(row, kb));
        aL[mi] = *(const bf16x8*)((const char*)MtL + swz(row, kb));
      }
#pragma unroll
      for (int ni = 0; ni < 4; ++ni) {
        const int row = (ni << 4) + li;
        const int off = swz(row, kb);
        const bf16x8 bH = *(const bf16x8*)((const char*)KtH + off);
        const bf16x8 bL = *(const bf16x8*)((const char*)KtL + off);
#pragma unroll
        for (int mi = 0; mi < 2; ++mi) {
          acc[mi][ni] = __builtin_amdgcn_mfma_f32_16x16x32_bf16(aH[mi], bH, acc[mi][ni], 0, 0, 0);
          acc[mi][ni] = __builtin_amdgcn_mfma_f32_16x16x32_bf16(aH[mi], bL, acc[mi][ni], 0, 0, 0);
          acc[mi][ni] = __builtin_amdgcn_mfma_f32_16x16x32_bf16(aL[mi], bH, acc[mi][ni], 0, 0, 0);
        }
      }
    }
  }
  const size_t base = (size_t)bh * 2048 * 64;
#pragma unroll
  for (int mi = 0; mi < 2; ++mi)
#pragma unroll
    for (int r = 0; r < 4; ++r) {
      const int trow = t0 + (w << 5) + (mi << 4) + (g << 2) + r;
#pragma unroll
      for (int ni = 0; ni < 4; ++ni) {
        const float x = acc[mi][ni][r];
        const unsigned short hh = f2bf(x);
        const size_t idx = base + (size_t)trow * 64 + (ni << 4) + li;
        KMh[idx] = hh;
        KMl[idx] = f2bf(x - bf2f(hh));
      }
    }
}

// ---------------------------------------------------------------------------
// attn32: block = 128 q-rows (4 waves x 32q), 32x32x16 MFMA, swapped operands.
// P built IN-REGISTER (cvt_pk + permlane32_swap), lsum via ones-MFMA,
// defer-max rescale. Double-buffered K/V staging, complementary CU pairing.
// ---------------------------------------------------------------------------
__global__ __launch_bounds__(256, 2) void attn32(
    const float* __restrict__ Q, const unsigned short* __restrict__ KMh,
    const unsigned short* __restrict__ KMl, const unsigned short* __restrict__ Vt,
    float* __restrict__ Out) {
  // LDS: 2 staging buffers x {KH 8KB, KL 8KB, VT 8KB} = 48KB
  __shared__ __attribute__((aligned(16))) unsigned short sm[24576];
  const int tid = threadIdx.x, lane = tid & 63, w = tid >> 6;
  const int g2 = lane >> 5, li5 = lane & 31;

  const int bid = (int)blockIdx.x;
  const int x = bid & 7;
  const int r = bid >> 3;
  const int m = r >> 2;
  const int bh = (x << 2) | (r & 3);
  const int lt = (m < 8) ? (15 - m) : (m - 8);
  const int b = bh >> 3, h = bh & 7;
  const int l0 = lt << 7;
  const int qg = l0 + (w << 5) + li5;

  // Q fragments (hi/lo) in registers, pre-scaled by 0.125*log2(e).
  const float SC2 = 0.18033688011112042f;
  bf16x8 qh[4], ql[4];
  {
    const float* qsrc = Q + (((size_t)(b * 2048 + qg) * 8 + h) << 6) + (g2 << 3);
#pragma unroll
    for (int kk = 0; kk < 4; ++kk) {
      const float4 v0 = *(const float4*)(qsrc + 16 * kk);
      const float4 v1 = *(const float4*)(qsrc + 16 * kk + 4);
      const float xs[8] = {v0.x, v0.y, v0.z, v0.w, v1.x, v1.y, v1.z, v1.w};
#pragma unroll
      for (int j = 0; j < 8; ++j) {
        const float xv = xs[j] * SC2;
        const unsigned short hh = f2bf(xv);
        qh[kk][j] = (short)hh;
        ql[kk][j] = (short)f2bf(xv - bf2f(hh));
      }
    }
  }

  f32x16 o0 = {0,0,0,0,0,0,0,0,0,0,0,0,0,0,0,0};
  f32x16 o1 = {0,0,0,0,0,0,0,0,0,0,0,0,0,0,0,0};
  f32x16 lsacc = {0,0,0,0,0,0,0,0,0,0,0,0,0,0,0,0};
  float m2 = -1e30f;
  bf16x8 ones;
#pragma unroll
  for (int j = 0; j < 8; ++j) ones[j] = (short)0x3F80;  // bf16 1.0

  const unsigned short* KHb = KMh + (size_t)bh * 2048 * 64;
  const unsigned short* KLb = KMl + (size_t)bh * 2048 * 64;
  const unsigned short* VTb = Vt + (size_t)bh * 64 * 2048;

  const int jtmax_blk = 2 * lt + 1;
  const int jtmax_w = 2 * lt + (w >> 1);

  // prologue: stage tile 0 into buffer 0
  {
    unsigned short* s0b = sm;
    stage_tile(KHb, 64, s0b, 64, tid);
    stage_tile(KLb, 64, s0b + 4096, 64, tid);
    stage_tile(VTb, 2048, s0b + 8192, 64, tid);
  }
  asm volatile("s_waitcnt vmcnt(0)" ::: "memory");
  __builtin_amdgcn_s_barrier();
  __builtin_amdgcn_sched_barrier(0);

  for (int jt = 0; jt <= jtmax_blk; ++jt) {
    const int cur = jt & 1;
    // prefetch next tile into the other buffer (overlaps this tile's compute)
    if (jt < jtmax_blk) {
      unsigned short* nb = sm + (cur ^ 1) * 12288;
      stage_tile(KHb + (size_t)(jt + 1) * 4096, 64, nb, 64, tid);
      stage_tile(KLb + (size_t)(jt + 1) * 4096, 64, nb + 4096, 64, tid);
      stage_tile(VTb + (jt + 1) * 64, 2048, nb + 8192, 64, tid);
    }

    if (jt <= jtmax_w) {
      const unsigned short* KH = sm + cur * 12288;
      const unsigned short* KL = KH + 4096;
      const unsigned short* VT = KH + 8192;

      // z = KM * Q : A = KM[t][e] rows (2 t-frags), B = Q regs (pre-scaled)
      f32x16 z0 = {0,0,0,0,0,0,0,0,0,0,0,0,0,0,0,0};
      f32x16 z1 = {0,0,0,0,0,0,0,0,0,0,0,0,0,0,0,0};
      __builtin_amdgcn_s_setprio(1);
#pragma unroll
      for (int kk = 0; kk < 4; ++kk) {
        const int cb = 32 * kk + 16 * g2;
        const bf16x8 a0h = *(const bf16x8*)((const char*)KH + swz(li5, cb));
        const bf16x8 a0l = *(const bf16x8*)((const char*)KL + swz(li5, cb));
        const bf16x8 a1h = *(const bf16x8*)((const char*)KH + swz(32 + li5, cb));
        const bf16x8 a1l = *(const bf16x8*)((const char*)KL + swz(32 + li5, cb));
        z0 = __builtin_amdgcn_mfma_f32_32x32x16_bf16(a0h, qh[kk], z0, 0, 0, 0);
        z0 = __builtin_amdgcn_mfma_f32_32x32x16_bf16(a0h, ql[kk], z0, 0, 0, 0);
        z0 = __builtin_amdgcn_mfma_f32_32x32x16_bf16(a0l, qh[kk], z0, 0, 0, 0);
        z1 = __builtin_amdgcn_mfma_f32_32x32x16_bf16(a1h, qh[kk], z1, 0, 0, 0);
        z1 = __builtin_amdgcn_mfma_f32_32x32x16_bf16(a1h, ql[kk], z1, 0, 0, 0);
        z1 = __builtin_amdgcn_mfma_f32_32x32x16_bf16(a1l, qh[kk], z1, 0, 0, 0);
      }
      __builtin_amdgcn_s_setprio(0);

      // causal mask (z pre-scaled; select only)
      const bool needmask = (jt * 64 + 63 > l0 + (w << 5));
      if (needmask) {
        const int thr = qg - jt * 64;  // mask if t_loc > thr
#pragma unroll
        for (int rr = 0; rr < 16; ++rr) {
          const int tl = (g2 << 2) + ((rr >> 2) << 3) + (rr & 3);
          if (tl > thr) z0[rr] = -1e30f;
          if (tl + 32 > thr) z1[rr] = -1e30f;
        }
      }

      // running max with deferred rescale (THR=11 in log2 domain)
      float t16[16];
#pragma unroll
      for (int rr = 0; rr < 16; ++rr) t16[rr] = fmaxf(z0[rr], z1[rr]);
#pragma unroll
      for (int s = 8; s; s >>= 1)
#pragma unroll
        for (int rr = 0; rr < 8; ++rr)
          if (rr < s) t16[rr] = fmaxf(t16[rr], t16[rr + s]);
      const float mx = fmaxf(t16[0], __shfl_xor(t16[0], 32));
      if (__any(mx > m2 + 11.0f)) {
        const float m2n = fmaxf(m2, mx);
        const float fs = exp2f(m2 - m2n);
        m2 = m2n;
#pragma unroll
        for (int rr = 0; rr < 16; ++rr) { o0[rr] *= fs; o1[rr] *= fs; }
        lsacc[0] *= fs;
      }

      // P = exp2(z - m2), packed to bf16 pairs in-register
      float pv0[16], pv1[16];
#pragma unroll
      for (int rr = 0; rr < 16; ++rr) {
        pv0[rr] = exp2f(z0[rr] - m2);
        pv1[rr] = exp2f(z1[rr] - m2);
      }
      unsigned int W0[8], W1[8];
#pragma unroll
      for (int i = 0; i < 8; ++i) {
        W0[i] = cvtpk(pv0[2 * i], pv0[2 * i + 1]);
        W1[i] = cvtpk(pv1[2 * i], pv1[2 * i + 1]);
      }
      // cross-half exchange: words [0..3] -> frag kk, [4..7] -> frag kk+1
      asm volatile("v_permlane32_swap_b32 %0, %1" : "+v"(W0[0]), "+v"(W0[2]));
      asm volatile("v_permlane32_swap_b32 %0, %1" : "+v"(W0[1]), "+v"(W0[3]));
      asm volatile("v_permlane32_swap_b32 %0, %1" : "+v"(W0[4]), "+v"(W0[6]));
      asm volatile("v_permlane32_swap_b32 %0, %1" : "+v"(W0[5]), "+v"(W0[7]));
      asm volatile("v_permlane32_swap_b32 %0, %1" : "+v"(W1[0]), "+v"(W1[2]));
      asm volatile("v_permlane32_swap_b32 %0, %1" : "+v"(W1[1]), "+v"(W1[3]));
      asm volatile("v_permlane32_swap_b32 %0, %1" : "+v"(W1[4]), "+v"(W1[6]));
      asm volatile("v_permlane32_swap_b32 %0, %1" : "+v"(W1[5]), "+v"(W1[7]));
      bf16x8 pf[4];
      {
        u32x4 f0 = {W0[0], W0[1], W0[2], W0[3]};
        u32x4 f1 = {W0[4], W0[5], W0[6], W0[7]};
        u32x4 f2 = {W1[0], W1[1], W1[2], W1[3]};
        u32x4 f3 = {W1[4], W1[5], W1[6], W1[7]};
        pf[0] = __builtin_bit_cast(bf16x8, f0);
        pf[1] = __builtin_bit_cast(bf16x8, f1);
        pf[2] = __builtin_bit_cast(bf16x8, f2);
        pf[3] = __builtin_bit_cast(bf16x8, f3);
      }

      // O += V^T * P ; lsum += ones * P   (P from registers)
      __builtin_amdgcn_s_setprio(1);
#pragma unroll
      for (int kk = 0; kk < 4; ++kk) {
        const int cb = 32 * kk + 16 * g2;
        const bf16x8 v0f = *(const bf16x8*)((const char*)VT + swz(li5, cb));
        const bf16x8 v1f = *(const bf16x8*)((const char*)VT + swz(32 + li5, cb));
        o0 = __builtin_amdgcn_mfma_f32_32x32x16_bf16(v0f, pf[kk], o0, 0, 0, 0);
        o1 = __builtin_amdgcn_mfma_f32_32x32x16_bf16(v1f, pf[kk], o1, 0, 0, 0);
        lsacc = __builtin_amdgcn_mfma_f32_32x32x16_bf16(ones, pf[kk], lsacc, 0, 0, 0);
      }
      __builtin_amdgcn_s_setprio(0);
    }

    // end-of-tile: drain this tile's prefetch, then block-wide barrier.
    asm volatile("s_waitcnt vmcnt(0)" ::: "memory");
    __builtin_amdgcn_s_barrier();
    __builtin_amdgcn_sched_barrier(0);
  }

  // epilogue: O[b, qg, h, d], d = df*32 + 4*g2 + 8*r2 + rr
  const float inv = 1.f / lsacc[0];
  float* ob = Out + (((size_t)(b * 2048 + qg) * 8 + h) << 6);
#pragma unroll
  for (int r2 = 0; r2 < 4; ++r2) {
    const int doff = (g2 << 2) + (r2 << 3);
    float4 s0 = make_float4(o0[4 * r2] * inv, o0[4 * r2 + 1] * inv,
                            o0[4 * r2 + 2] * inv, o0[4 * r2 + 3] * inv);
    *(float4*)(ob + doff) = s0;
    float4 s1 = make_float4(o1[4 * r2] * inv, o1[4 * r2 + 1] * inv,
                            o1[4 * r2 + 2] * inv, o1[4 * r2 + 3] * inv);
    *(float4*)(ob + 32 + doff) = s1;
  }
}

extern "C" void kernel_launch(void* const* d_in, const int* in_sizes, int n_in,
                              void* d_out, int out_size, void* d_ws, size_t ws_size,
                              hipStream_t stream) {
  const float* Q = (const float*)d_in[0];
  const float* K = (const float*)d_in[1];
  const float* V = (const float*)d_in[2];
  const float* M = (const float*)d_in[3];
  float* Out = (float*)d_out;
  char* ws = (char*)d_ws;
  const size_t MB = 1u << 20;
  unsigned short* Mth = (unsigned short*)(ws);            // [2048 t][2048 s]
  unsigned short* Mtl = (unsigned short*)(ws + 8 * MB);
  unsigned short* Kth = (unsigned short*)(ws + 16 * MB);  // [32 bh][64 e][2048 s]
  unsigned short* Ktl = (unsigned short*)(ws + 24 * MB);
  unsigned short* Vts = (unsigned short*)(ws + 32 * MB);  // [32 bh][64 d][2048 s]
  unsigned short* KMh = (unsigned short*)(ws + 40 * MB);  // [32 bh][2048 t][64 e]
  unsigned short* KMl = (unsigned short*)(ws + 48 * MB);

  prep_m<<<dim3(32, 32), 256, 0, stream>>>(M, Mth, Mtl);
  prep_kv<<<dim3(32, 32), 256, 0, stream>>>(K, Kth, Ktl, 1);
  prep_kv<<<dim3(32, 32), 256, 0, stream>>>(V, Vts, (unsigned short*)nullptr, 0);
  km_mfma<<<dim3(16, 32), 256, 0, stream>>>(Mth, Mtl, Kth, Ktl, KMh, KMl);
  attn32<<<dim3(512), 256, 0, stream>>>(Q, KMh, KMl, Vts, Out);
}